// Round 15
// baseline (102.990 us; speedup 1.0000x reference)
//
#include <hip/hip_runtime.h>

#define P_TERMS 24

typedef _Float16 f16x8 __attribute__((ext_vector_type(8)));
typedef float f32x16 __attribute__((ext_vector_type(16)));

static __device__ __forceinline__ unsigned pk2(float a, float b) {
  unsigned d;
  asm("v_cvt_pkrtz_f16_f32 %0, %1, %2" : "=v"(d) : "v"(a), "v"(b));
  return d;
}
// d.lo = a.lo + b.hi ; d.hi = a.hi + b.lo   (f16x2, swapped src1)
static __device__ __forceinline__ unsigned pkadd_sw(unsigned a, unsigned b) {
  unsigned d;
  asm("v_pk_add_f16 %0, %1, %2 op_sel:[0,1] op_sel_hi:[1,0]"
      : "=v"(d) : "v"(a), "v"(b));
  return d;
}

// -------- K0 (fused prep): chain cp[p]=A^pB per block; H8 rows + Ct8 ------
__global__ __launch_bounds__(256) void s4_prep(
    const float* __restrict__ A, const float* __restrict__ B,
    const float* __restrict__ C, const float* __restrict__ log_dt,
    _Float16* __restrict__ H8, _Float16* __restrict__ Ct8) {
  const int tid = threadIdx.x;
  const int bid = blockIdx.x;
  if (bid == 64) {  // Ct8[n/8][m][8] = C[m][n]
    const int m = tid;
#pragma unroll 1
    for (int n = 0; n < 64; ++n)
      Ct8[((size_t)(n >> 3) * 256 + m) * 8 + (n & 7)] = (_Float16)C[m * 64 + n];
    return;
  }
  __shared__ float cp[P_TERMS + 1][64];
  __shared__ float cur[64];
  if (tid < 64) { cur[tid] = B[tid]; cp[0][tid] = B[tid]; }
  __syncthreads();
  const int n = tid >> 2, g = tid & 3;
  for (int p = 1; p <= P_TERMS; ++p) {
    float s = 0.f;
    const int j0 = g * 16;
#pragma unroll
    for (int j = 0; j < 16; ++j) s += A[n * 64 + j0 + j] * cur[j0 + j];
    s += __shfl_xor(s, 1);
    s += __shfl_xor(s, 2);
    __syncthreads();
    if (g == 0) { cur[n] = s; cp[p][n] = s; }
    __syncthreads();
  }
  const float dt = __expf(log_dt[0]);
#pragma unroll 1
  for (int kk = tid; kk < 512; kk += 256) {
    float coef = 1.f, s = cp[0][bid];
#pragma unroll 1
    for (int p = 1; p <= P_TERMS; ++p) {
      coef *= dt * (float)(kk - p + 1) / (float)p;  // zero for p>kk
      s += coef * cp[p][bid];
    }
    H8[((size_t)(kk >> 3) * 64 + bid) * 8 + (kk & 7)] = (_Float16)s;
  }
}

// ---------------- Stage 1 (compute): Z[ch][t][n] f16 into ws -------------
__global__ __launch_bounds__(256, 4) void s4_stage1(
    const float* __restrict__ x, const _Float16* __restrict__ H8,
    _Float16* __restrict__ Zws) {
  __shared__ float us[512];
  __shared__ uint4 UF8[1536];

  const int tid = threadIdx.x;
  const int bid = blockIdx.x;
  const int th = bid & 1;
  const int ch = bid >> 1;
  const int b = ch >> 8;
  const int d = ch & 255;

  for (int i = tid; i < 512; i += 256) us[i] = x[(b * 512 + i) * 256 + d];
  __syncthreads();
  {
    const int i0 = tid * 6;
    float w[14];
#pragma unroll
    for (int j = 0; j < 14; ++j) {
      const int g = i0 + j - 512;
      const float v = us[g & 511];
      w[j] = (g >= 0 && g < 512) ? v : 0.f;
    }
    unsigned P[13];
#pragma unroll
    for (int j = 0; j < 13; ++j) P[j] = pk2(w[j], w[j + 1]);
#pragma unroll
    for (int e = 0; e < 6; ++e)
      UF8[i0 + e] = make_uint4(P[e], P[e + 2], P[e + 4], P[e + 6]);
  }
  __syncthreads();

  const int lane = tid & 63;
  const int wid = tid >> 6;
  const int r = lane & 31;
  const int hi = lane >> 5;
  const int tw = wid * 64;
  const int tg0 = th * 256 + tw;

  f32x16 acc[2][2];
#pragma unroll
  for (int ti = 0; ti < 2; ++ti)
#pragma unroll
    for (int ni = 0; ni < 2; ++ni)
#pragma unroll
      for (int e = 0; e < 16; ++e) acc[ti][ni][e] = 0.f;

  int ifj = 512 + tg0 + r + hi * 8;
  int irj = 505 + tg0 + r - hi * 8;
  const _Float16* hp = H8 + hi * 512 + r * 8;

#pragma unroll 1
  for (int j = 0; j < 32; ++j) {
    const uint4 F0 = UF8[ifj];
    const uint4 R0 = UF8[irj];
    const uint4 F1 = UF8[ifj + 32];
    const uint4 R1 = UF8[irj + 32];
    const f16x8 h0 = *reinterpret_cast<const f16x8*>(hp);
    const f16x8 h1 = *reinterpret_cast<const f16x8*>(hp + 256);
    union { unsigned w[4]; f16x8 v; } g0, g1;
    g0.w[0] = pkadd_sw(F0.x, R0.w);
    g0.w[1] = pkadd_sw(F0.y, R0.z);
    g0.w[2] = pkadd_sw(F0.z, R0.y);
    g0.w[3] = pkadd_sw(F0.w, R0.x);
    g1.w[0] = pkadd_sw(F1.x, R1.w);
    g1.w[1] = pkadd_sw(F1.y, R1.z);
    g1.w[2] = pkadd_sw(F1.z, R1.y);
    g1.w[3] = pkadd_sw(F1.w, R1.x);
    __builtin_amdgcn_s_setprio(1);
    acc[0][0] = __builtin_amdgcn_mfma_f32_32x32x16_f16(h0, g0.v, acc[0][0], 0, 0, 0);
    acc[0][1] = __builtin_amdgcn_mfma_f32_32x32x16_f16(h1, g0.v, acc[0][1], 0, 0, 0);
    acc[1][0] = __builtin_amdgcn_mfma_f32_32x32x16_f16(h0, g1.v, acc[1][0], 0, 0, 0);
    acc[1][1] = __builtin_amdgcn_mfma_f32_32x32x16_f16(h1, g1.v, acc[1][1], 0, 0, 0);
    __builtin_amdgcn_s_setprio(0);
    ifj += 16;
    irj -= 16;
    hp += 1024;
  }

  // in-register transpose (verified R13): zfrag[ti][ks] elem e <-> n=16ks+8hi+e
  f16x8 zfrag[2][4];
#pragma unroll
  for (int ti = 0; ti < 2; ++ti) {
#pragma unroll
    for (int ks = 0; ks < 4; ++ks) {
      const int ni = ks >> 1;
      const int qe = (2 * ks) & 3;
      const int qo = qe + 1;
      unsigned W0 = pk2(acc[ti][ni][4 * qe + 0], acc[ti][ni][4 * qe + 1]);
      unsigned W2 = pk2(acc[ti][ni][4 * qo + 0], acc[ti][ni][4 * qo + 1]);
      unsigned W1 = pk2(acc[ti][ni][4 * qe + 2], acc[ti][ni][4 * qe + 3]);
      unsigned W3 = pk2(acc[ti][ni][4 * qo + 2], acc[ti][ni][4 * qo + 3]);
      asm("v_permlane32_swap_b32 %0, %1" : "+v"(W0), "+v"(W2));
      asm("v_permlane32_swap_b32 %0, %1" : "+v"(W1), "+v"(W3));
      union { unsigned w[4]; f16x8 v; } zf;
      zf.w[0] = W0;
      zf.w[1] = W1;
      zf.w[2] = W2;
      zf.w[3] = W3;
      zfrag[ti][ks] = zf.v;
    }
  }

  // store Z[ch][t][n]: chunk c=2ks+hi at n=c*8
  _Float16* zb = Zws + ((size_t)(b * 256 + d)) * 32768;
#pragma unroll
  for (int ti = 0; ti < 2; ++ti) {
    const int t = tg0 + ti * 32 + r;
#pragma unroll
    for (int ks = 0; ks < 4; ++ks)
      *reinterpret_cast<f16x8*>(zb + t * 64 + (2 * ks + hi) * 8) = zfrag[ti][ks];
  }
}

// ---------------- Stage 2 (streaming): Y[t][d][m] = dt*Z@C^T + 2uD --------
// Block = (b, t-tile 8, d-quarter 64). A-rows = d (regs), cols m (lanes):
// (d,m) contiguous for fixed t -> wave store stream is linear ~32KB runs.
__global__ __launch_bounds__(256, 2) void s4_stage2(
    const float* __restrict__ x, const _Float16* __restrict__ Zws,
    const _Float16* __restrict__ Ct8, const float* __restrict__ Dvec,
    const float* __restrict__ log_dt, float* __restrict__ out) {
  __shared__ _Float16 zt[64 * 8 * 64];  // [d][t][c^swz][8]
  __shared__ float us2[8 * 64];

  const int tid = threadIdx.x;
  const int bid = blockIdx.x;
  const int ds = bid & 3;
  const int tt = (bid >> 2) & 63;
  const int b = bid >> 8;

  for (int p = tid; p < 512; p += 256) {
    const int t = p >> 6, dl = p & 63;
    us2[p] = x[((size_t)(b * 512) + tt * 8 + t) * 256 + ds * 64 + dl];
  }
  const _Float16* zsrc =
      Zws + ((size_t)(b * 256) + ds * 64) * 32768 + (size_t)tt * 8 * 64;
#pragma unroll 1
  for (int i = 0; i < 16; ++i) {
    const int p = tid + 256 * i;  // 16B piece
    const int dd = p >> 6;
    const int t = (p >> 3) & 7, c = p & 7;
    const f16x8 v =
        *reinterpret_cast<const f16x8*>(zsrc + (size_t)dd * 32768 + t * 64 + c * 8);
    *reinterpret_cast<f16x8*>(&zt[((dd * 8 + t) * 8 + (c ^ (dd & 7))) * 8]) = v;
  }
  __syncthreads();

  const int lane = tid & 63;
  const int wid = tid >> 6;
  const int r = lane & 31;
  const int hi = lane >> 5;
  const int dt = wid & 1;   // d half (32)
  const int tp = wid >> 1;  // t half (4)
  const float dtv = __expf(log_dt[0]);
  const int dl_lane = dt * 32 + r;

  float Dv[8];
#pragma unroll
  for (int mi = 0; mi < 8; ++mi) Dv[mi] = Dvec[mi * 32 + r];

#pragma unroll 1
  for (int tl = 0; tl < 4; ++tl) {
    const int tloc = tp * 4 + tl;
    const int tglob = tt * 8 + tloc;

    f16x8 af[4];
#pragma unroll
    for (int ks = 0; ks < 4; ++ks) {
      const int c = ks * 2 + hi;
      af[ks] = *reinterpret_cast<const f16x8*>(
          &zt[((dl_lane * 8 + tloc) * 8 + (c ^ (dl_lane & 7))) * 8]);
    }

    f32x16 y[8];
#pragma unroll
    for (int mi = 0; mi < 8; ++mi)
#pragma unroll
      for (int e = 0; e < 16; ++e) y[mi][e] = 0.f;

#pragma unroll
    for (int mi = 0; mi < 8; ++mi) {
#pragma unroll
      for (int ks = 0; ks < 4; ++ks) {
        const f16x8 bf = *reinterpret_cast<const f16x8*>(
            Ct8 + ((size_t)(2 * ks + hi) * 256 + mi * 32 + r) * 8);
        __builtin_amdgcn_s_setprio(1);
        y[mi] = __builtin_amdgcn_mfma_f32_32x32x16_f16(af[ks], bf, y[mi], 0, 0, 0);
        __builtin_amdgcn_s_setprio(0);
      }
    }

#pragma unroll
    for (int reg = 0; reg < 16; ++reg) {
      const int dl = dt * 32 + (reg & 3) + 8 * (reg >> 2) + 4 * hi;
      const float uv2 = 2.f * us2[tloc * 64 + dl];
      float* orow =
          out + (((size_t)b * 512 + tglob) * 256 + ds * 64 + dl) * 256;
#pragma unroll
      for (int mi = 0; mi < 8; ++mi)
        orow[mi * 32 + r] = dtv * y[mi][reg] + uv2 * Dv[mi];
    }
  }
}

// ---------------- Fallback (ws too small): R12 fused kernel ---------------
__global__ __launch_bounds__(256, 2) void s4_fused(
    const float* __restrict__ x, const _Float16* __restrict__ H8,
    const _Float16* __restrict__ Ct8, const float* __restrict__ Dvec,
    const float* __restrict__ log_dt, float* __restrict__ out) {
  __shared__ float us[512];
  __shared__ uint4 UF8[1536];
  __shared__ unsigned Zl[256][34];

  const int tid = threadIdx.x;
  const int ch = blockIdx.x;
  const int b = ch >> 8;
  const int d = ch & 255;

  for (int i = tid; i < 512; i += 256) us[i] = x[(b * 512 + i) * 256 + d];
  __syncthreads();
  {
    const int i0 = tid * 6;
    float w[14];
#pragma unroll
    for (int j = 0; j < 14; ++j) {
      const int g = i0 + j - 512;
      const float v = us[g & 511];
      w[j] = (g >= 0 && g < 512) ? v : 0.f;
    }
    unsigned P[13];
#pragma unroll
    for (int j = 0; j < 13; ++j) P[j] = pk2(w[j], w[j + 1]);
#pragma unroll
    for (int e = 0; e < 6; ++e)
      UF8[i0 + e] = make_uint4(P[e], P[e + 2], P[e + 4], P[e + 6]);
  }
  __syncthreads();

  const int lane = tid & 63;
  const int wid = tid >> 6;
  const int r = lane & 31;
  const int hi = lane >> 5;
  const int tw = wid * 64;
  const int tl0 = tw + r;
  const float dtv = __expf(log_dt[0]);

  auto s1_step = [&](int& ifj, int& irj, const _Float16*& hp, f32x16 acc[2][2]) {
    const uint4 F0 = UF8[ifj];
    const uint4 R0 = UF8[irj];
    const uint4 F1 = UF8[ifj + 32];
    const uint4 R1 = UF8[irj + 32];
    const f16x8 h0 = *reinterpret_cast<const f16x8*>(hp);
    const f16x8 h1 = *reinterpret_cast<const f16x8*>(hp + 256);
    union { unsigned w[4]; f16x8 v; } g0, g1;
    g0.w[0] = pkadd_sw(F0.x, R0.w);
    g0.w[1] = pkadd_sw(F0.y, R0.z);
    g0.w[2] = pkadd_sw(F0.z, R0.y);
    g0.w[3] = pkadd_sw(F0.w, R0.x);
    g1.w[0] = pkadd_sw(F1.x, R1.w);
    g1.w[1] = pkadd_sw(F1.y, R1.z);
    g1.w[2] = pkadd_sw(F1.z, R1.y);
    g1.w[3] = pkadd_sw(F1.w, R1.x);
    __builtin_amdgcn_s_setprio(1);
    acc[0][0] = __builtin_amdgcn_mfma_f32_32x32x16_f16(h0, g0.v, acc[0][0], 0, 0, 0);
    acc[0][1] = __builtin_amdgcn_mfma_f32_32x32x16_f16(h1, g0.v, acc[0][1], 0, 0, 0);
    acc[1][0] = __builtin_amdgcn_mfma_f32_32x32x16_f16(h0, g1.v, acc[1][0], 0, 0, 0);
    acc[1][1] = __builtin_amdgcn_mfma_f32_32x32x16_f16(h1, g1.v, acc[1][1], 0, 0, 0);
    __builtin_amdgcn_s_setprio(0);
    ifj += 16;
    irj -= 16;
    hp += 1024;
  };

  auto writeZ = [&](f32x16 acc[2][2]) {
#pragma unroll
    for (int ti = 0; ti < 2; ++ti) {
      const int t = tl0 + ti * 32;
#pragma unroll
      for (int ni = 0; ni < 2; ++ni) {
#pragma unroll
        for (int q = 0; q < 4; ++q) {
          uint2 v;
          v.x = pk2(acc[ti][ni][4 * q + 0], acc[ti][ni][4 * q + 1]);
          v.y = pk2(acc[ti][ni][4 * q + 2], acc[ti][ni][4 * q + 3]);
          *reinterpret_cast<uint2*>(&Zl[t][ni * 16 + q * 4 + 2 * hi]) = v;
        }
      }
    }
  };

  auto s2_panel = [&](int mp, int th) {
    const int mb2 = mp * 64;
    f32x16 y[2][2];
#pragma unroll
    for (int ti = 0; ti < 2; ++ti)
#pragma unroll
      for (int mi = 0; mi < 2; ++mi)
#pragma unroll
        for (int e = 0; e < 16; ++e) y[ti][mi][e] = 0.f;
#pragma unroll
    for (int ks = 0; ks < 4; ++ks) {
      const int c0 = 8 * ks + 4 * hi;
      union { uint2 u[2]; f16x8 v; } z0, z1;
      z0.u[0] = *reinterpret_cast<const uint2*>(&Zl[tl0][c0]);
      z0.u[1] = *reinterpret_cast<const uint2*>(&Zl[tl0][c0 + 2]);
      z1.u[0] = *reinterpret_cast<const uint2*>(&Zl[tl0 + 32][c0]);
      z1.u[1] = *reinterpret_cast<const uint2*>(&Zl[tl0 + 32][c0 + 2]);
      const _Float16* cb = Ct8 + ((size_t)(2 * ks + hi) * 256 + mb2 + r) * 8;
      const f16x8 c0f = *reinterpret_cast<const f16x8*>(cb);
      const f16x8 c1f = *reinterpret_cast<const f16x8*>(cb + 256);
      __builtin_amdgcn_s_setprio(1);
      y[0][0] = __builtin_amdgcn_mfma_f32_32x32x16_f16(z0.v, c0f, y[0][0], 0, 0, 0);
      y[0][1] = __builtin_amdgcn_mfma_f32_32x32x16_f16(z0.v, c1f, y[0][1], 0, 0, 0);
      y[1][0] = __builtin_amdgcn_mfma_f32_32x32x16_f16(z1.v, c0f, y[1][0], 0, 0, 0);
      y[1][1] = __builtin_amdgcn_mfma_f32_32x32x16_f16(z1.v, c1f, y[1][1], 0, 0, 0);
      __builtin_amdgcn_s_setprio(0);
    }
#pragma unroll
    for (int ti = 0; ti < 2; ++ti) {
      const int tb2 = th * 256 + tw + ti * 32 + 4 * hi;
#pragma unroll
      for (int mi = 0; mi < 2; ++mi) {
        const int m = mb2 + mi * 32 + r;
        const float Dm = Dvec[m];
#pragma unroll
        for (int reg = 0; reg < 16; ++reg) {
          const int trow = tb2 + (reg & 3) + 8 * (reg >> 2);
          const float uv = us[trow];
          out[(((size_t)b * 512 + trow) * 256 + d) * 256 + m] =
              dtv * y[ti][mi][reg] + 2.f * uv * Dm;
        }
      }
    }
  };

  f32x16 acc[2][2];
#pragma unroll
  for (int ti = 0; ti < 2; ++ti)
#pragma unroll
    for (int ni = 0; ni < 2; ++ni)
#pragma unroll
      for (int e = 0; e < 16; ++e) acc[ti][ni][e] = 0.f;
  {
    int ifj = 512 + tw + r + hi * 8;
    int irj = 505 + tw + r - hi * 8;
    const _Float16* hp = H8 + hi * 512 + r * 8;
#pragma unroll 1
    for (int j = 0; j < 32; ++j) s1_step(ifj, irj, hp, acc);
  }
  writeZ(acc);
  {
    int ifj = 512 + 256 + tw + r + hi * 8;
    int irj = 505 + 256 + tw + r - hi * 8;
    const _Float16* hp = H8 + hi * 512 + r * 8;
    f32x16 acc1[2][2];
#pragma unroll
    for (int ti = 0; ti < 2; ++ti)
#pragma unroll
      for (int ni = 0; ni < 2; ++ni)
#pragma unroll
        for (int e = 0; e < 16; ++e) acc1[ti][ni][e] = 0.f;
#pragma unroll 1
    for (int s = 0; s < 4; ++s) {
#pragma unroll 1
      for (int j2 = 0; j2 < 8; ++j2) s1_step(ifj, irj, hp, acc1);
      s2_panel(s, 0);
    }
    writeZ(acc1);
  }
#pragma unroll 1
  for (int s = 0; s < 4; ++s) s2_panel(s, 1);
}

extern "C" void kernel_launch(void* const* d_in, const int* in_sizes, int n_in,
                              void* d_out, int out_size, void* d_ws, size_t ws_size,
                              hipStream_t stream) {
  (void)in_sizes; (void)n_in; (void)out_size;
  const float* x = (const float*)d_in[0];
  const float* A = (const float*)d_in[1];
  const float* B = (const float*)d_in[2];
  const float* C = (const float*)d_in[3];
  const float* D = (const float*)d_in[4];
  const float* log_dt = (const float*)d_in[5];
  float* out = (float*)d_out;

  _Float16* H8 = (_Float16*)d_ws;                    // 64 KB
  _Float16* Ct8 = (_Float16*)((char*)d_ws + 65536);  // 32 KB
  _Float16* Zws = (_Float16*)((char*)d_ws + 131072); // 32 MB

  s4_prep<<<65, 256, 0, stream>>>(A, B, C, log_dt, H8, Ct8);
  if (ws_size >= (size_t)131072 + (size_t)33554432) {
    s4_stage1<<<1024, 256, 0, stream>>>(x, H8, Zws);
    s4_stage2<<<512, 256, 0, stream>>>(x, Zws, Ct8, D, log_dt, out);
  } else {
    s4_fused<<<512, 256, 0, stream>>>(x, H8, Ct8, D, log_dt, out);
  }
}

// Round 16
// 81.469 us; speedup vs baseline: 1.2642x; 1.2642x over previous
//
#include <hip/hip_runtime.h>

#define P_TERMS 24

typedef _Float16 f16x8 __attribute__((ext_vector_type(8)));
typedef float f32x16 __attribute__((ext_vector_type(16)));

static __device__ __forceinline__ unsigned pk2(float a, float b) {
  unsigned d;
  asm("v_cvt_pkrtz_f16_f32 %0, %1, %2" : "=v"(d) : "v"(a), "v"(b));
  return d;
}
// d.lo = a.lo + b.hi ; d.hi = a.hi + b.lo   (f16x2, swapped src1)
static __device__ __forceinline__ unsigned pkadd_sw(unsigned a, unsigned b) {
  unsigned d;
  asm("v_pk_add_f16 %0, %1, %2 op_sel:[0,1] op_sel_hi:[1,0]"
      : "=v"(d) : "v"(a), "v"(b));
  return d;
}

// -------- K0 (fused prep): chain cp[p]=A^pB per block; H8 rows + Ct8 ------
__global__ __launch_bounds__(256) void s4_prep(
    const float* __restrict__ A, const float* __restrict__ B,
    const float* __restrict__ C, const float* __restrict__ log_dt,
    _Float16* __restrict__ H8, _Float16* __restrict__ Ct8) {
  const int tid = threadIdx.x;
  const int bid = blockIdx.x;
  if (bid == 64) {  // Ct8[n/8][m][8] = C[m][n]
    const int m = tid;
#pragma unroll 1
    for (int n = 0; n < 64; ++n)
      Ct8[((size_t)(n >> 3) * 256 + m) * 8 + (n & 7)] = (_Float16)C[m * 64 + n];
    return;
  }
  __shared__ float cp[P_TERMS + 1][64];
  __shared__ float cur[64];
  if (tid < 64) { cur[tid] = B[tid]; cp[0][tid] = B[tid]; }
  __syncthreads();
  const int n = tid >> 2, g = tid & 3;
  for (int p = 1; p <= P_TERMS; ++p) {
    float s = 0.f;
    const int j0 = g * 16;
#pragma unroll
    for (int j = 0; j < 16; ++j) s += A[n * 64 + j0 + j] * cur[j0 + j];
    s += __shfl_xor(s, 1);
    s += __shfl_xor(s, 2);
    __syncthreads();
    if (g == 0) { cur[n] = s; cp[p][n] = s; }
    __syncthreads();
  }
  const float dt = __expf(log_dt[0]);
#pragma unroll 1
  for (int kk = tid; kk < 512; kk += 256) {
    float coef = 1.f, s = cp[0][bid];
#pragma unroll 1
    for (int p = 1; p <= P_TERMS; ++p) {
      coef *= dt * (float)(kk - p + 1) / (float)p;  // zero for p>kk
      s += coef * cp[p][bid];
    }
    H8[((size_t)(kk >> 3) * 64 + bid) * 8 + (kk & 7)] = (_Float16)s;
  }
}

// ---------------- Main: rank-64 factored  Y = dt*(G@H^T)@C^T + 2 u D ------
// One block = one full channel (512 t). Per wave: stage1(th0) -> Zl ->
// INTERLEAVE{ stage1(th1) k-chunks with stage2(th0) store panels } ->
// Zl(th1) -> stage2(th1). Zl rows wave-private: no barriers after build.
__global__ __launch_bounds__(256, 2) void s4_main(
    const float* __restrict__ x, const _Float16* __restrict__ H8,
    const _Float16* __restrict__ Ct8, const float* __restrict__ Dvec,
    const float* __restrict__ log_dt, float* __restrict__ out) {
  __shared__ float us[512];
  __shared__ uint4 UF8[1536];
  __shared__ unsigned Zl[256][34];

  const int tid = threadIdx.x;
  const int ch = blockIdx.x;
  const int b = ch >> 8;
  const int d = ch & 255;

  for (int i = tid; i < 512; i += 256) us[i] = x[(b * 512 + i) * 256 + d];
  __syncthreads();
  {
    const int i0 = tid * 6;
    float w[14];
#pragma unroll
    for (int j = 0; j < 14; ++j) {
      const int g = i0 + j - 512;
      const float v = us[g & 511];
      w[j] = (g >= 0 && g < 512) ? v : 0.f;
    }
    unsigned P[13];
#pragma unroll
    for (int j = 0; j < 13; ++j) P[j] = pk2(w[j], w[j + 1]);
#pragma unroll
    for (int e = 0; e < 6; ++e)
      UF8[i0 + e] = make_uint4(P[e], P[e + 2], P[e + 4], P[e + 6]);
  }
  __syncthreads();

  const int lane = tid & 63;
  const int wid = tid >> 6;
  const int r = lane & 31;
  const int hi = lane >> 5;
  const int tw = wid * 64;
  const int tl0 = tw + r;
  const float dtv = __expf(log_dt[0]);

  auto s1_step = [&](int& ifj, int& irj, const _Float16*& hp, f32x16 acc[2][2]) {
    const uint4 F0 = UF8[ifj];
    const uint4 R0 = UF8[irj];
    const uint4 F1 = UF8[ifj + 32];
    const uint4 R1 = UF8[irj + 32];
    const f16x8 h0 = *reinterpret_cast<const f16x8*>(hp);
    const f16x8 h1 = *reinterpret_cast<const f16x8*>(hp + 256);
    union { unsigned w[4]; f16x8 v; } g0, g1;
    g0.w[0] = pkadd_sw(F0.x, R0.w);
    g0.w[1] = pkadd_sw(F0.y, R0.z);
    g0.w[2] = pkadd_sw(F0.z, R0.y);
    g0.w[3] = pkadd_sw(F0.w, R0.x);
    g1.w[0] = pkadd_sw(F1.x, R1.w);
    g1.w[1] = pkadd_sw(F1.y, R1.z);
    g1.w[2] = pkadd_sw(F1.z, R1.y);
    g1.w[3] = pkadd_sw(F1.w, R1.x);
    __builtin_amdgcn_s_setprio(1);
    acc[0][0] = __builtin_amdgcn_mfma_f32_32x32x16_f16(h0, g0.v, acc[0][0], 0, 0, 0);
    acc[0][1] = __builtin_amdgcn_mfma_f32_32x32x16_f16(h1, g0.v, acc[0][1], 0, 0, 0);
    acc[1][0] = __builtin_amdgcn_mfma_f32_32x32x16_f16(h0, g1.v, acc[1][0], 0, 0, 0);
    acc[1][1] = __builtin_amdgcn_mfma_f32_32x32x16_f16(h1, g1.v, acc[1][1], 0, 0, 0);
    __builtin_amdgcn_s_setprio(0);
    ifj += 16;
    irj -= 16;
    hp += 1024;
  };

  auto writeZ = [&](f32x16 acc[2][2]) {
#pragma unroll
    for (int ti = 0; ti < 2; ++ti) {
      const int t = tl0 + ti * 32;
#pragma unroll
      for (int ni = 0; ni < 2; ++ni) {
#pragma unroll
        for (int q = 0; q < 4; ++q) {
          uint2 v;
          v.x = pk2(acc[ti][ni][4 * q + 0], acc[ti][ni][4 * q + 1]);
          v.y = pk2(acc[ti][ni][4 * q + 2], acc[ti][ni][4 * q + 3]);
          *reinterpret_cast<uint2*>(&Zl[t][ni * 16 + q * 4 + 2 * hi]) = v;
        }
      }
    }
  };

  auto s2_panel = [&](int mp, int th) {
    const int mb2 = mp * 64;
    f32x16 y[2][2];
#pragma unroll
    for (int ti = 0; ti < 2; ++ti)
#pragma unroll
      for (int mi = 0; mi < 2; ++mi)
#pragma unroll
        for (int e = 0; e < 16; ++e) y[ti][mi][e] = 0.f;
#pragma unroll
    for (int ks = 0; ks < 4; ++ks) {
      const int c0 = 8 * ks + 4 * hi;
      union { uint2 u[2]; f16x8 v; } z0, z1;
      z0.u[0] = *reinterpret_cast<const uint2*>(&Zl[tl0][c0]);
      z0.u[1] = *reinterpret_cast<const uint2*>(&Zl[tl0][c0 + 2]);
      z1.u[0] = *reinterpret_cast<const uint2*>(&Zl[tl0 + 32][c0]);
      z1.u[1] = *reinterpret_cast<const uint2*>(&Zl[tl0 + 32][c0 + 2]);
      const _Float16* cb = Ct8 + ((size_t)(2 * ks + hi) * 256 + mb2 + r) * 8;
      const f16x8 c0f = *reinterpret_cast<const f16x8*>(cb);
      const f16x8 c1f = *reinterpret_cast<const f16x8*>(cb + 256);
      __builtin_amdgcn_s_setprio(1);
      y[0][0] = __builtin_amdgcn_mfma_f32_32x32x16_f16(z0.v, c0f, y[0][0], 0, 0, 0);
      y[0][1] = __builtin_amdgcn_mfma_f32_32x32x16_f16(z0.v, c1f, y[0][1], 0, 0, 0);
      y[1][0] = __builtin_amdgcn_mfma_f32_32x32x16_f16(z1.v, c0f, y[1][0], 0, 0, 0);
      y[1][1] = __builtin_amdgcn_mfma_f32_32x32x16_f16(z1.v, c1f, y[1][1], 0, 0, 0);
      __builtin_amdgcn_s_setprio(0);
    }
#pragma unroll
    for (int ti = 0; ti < 2; ++ti) {
      const int tb2 = th * 256 + tw + ti * 32 + 4 * hi;
#pragma unroll
      for (int mi = 0; mi < 2; ++mi) {
        const int m = mb2 + mi * 32 + r;
        const float Dm = Dvec[m];
#pragma unroll
        for (int reg = 0; reg < 16; ++reg) {
          const int trow = tb2 + (reg & 3) + 8 * (reg >> 2);
          const float uv = us[trow];
          out[(((size_t)b * 512 + trow) * 256 + d) * 256 + m] =
              dtv * y[ti][mi][reg] + 2.f * uv * Dm;
        }
      }
    }
  };

  // ================= schedule =================
  f32x16 acc[2][2];
#pragma unroll
  for (int ti = 0; ti < 2; ++ti)
#pragma unroll
    for (int ni = 0; ni < 2; ++ni)
#pragma unroll
      for (int e = 0; e < 16; ++e) acc[ti][ni][e] = 0.f;

  {
    int ifj = 512 + tw + r + hi * 8;
    int irj = 505 + tw + r - hi * 8;
    const _Float16* hp = H8 + hi * 512 + r * 8;
#pragma unroll 1
    for (int j = 0; j < 32; ++j) s1_step(ifj, irj, hp, acc);
  }
  writeZ(acc);

  {
    int ifj = 512 + 256 + tw + r + hi * 8;
    int irj = 505 + 256 + tw + r - hi * 8;
    const _Float16* hp = H8 + hi * 512 + r * 8;
    f32x16 acc1[2][2];
#pragma unroll
    for (int ti = 0; ti < 2; ++ti)
#pragma unroll
      for (int ni = 0; ni < 2; ++ni)
#pragma unroll
        for (int e = 0; e < 16; ++e) acc1[ti][ni][e] = 0.f;

#pragma unroll 1
    for (int s = 0; s < 4; ++s) {
#pragma unroll 1
      for (int j2 = 0; j2 < 8; ++j2) s1_step(ifj, irj, hp, acc1);
      s2_panel(s, 0);
    }
    writeZ(acc1);
  }

#pragma unroll 1
  for (int s = 0; s < 4; ++s) s2_panel(s, 1);
}

extern "C" void kernel_launch(void* const* d_in, const int* in_sizes, int n_in,
                              void* d_out, int out_size, void* d_ws, size_t ws_size,
                              hipStream_t stream) {
  (void)in_sizes; (void)n_in; (void)out_size; (void)ws_size;
  const float* x = (const float*)d_in[0];
  const float* A = (const float*)d_in[1];
  const float* B = (const float*)d_in[2];
  const float* C = (const float*)d_in[3];
  const float* D = (const float*)d_in[4];
  const float* log_dt = (const float*)d_in[5];
  float* out = (float*)d_out;

  _Float16* H8 = (_Float16*)d_ws;                    // 512*64*2 = 64 KB
  _Float16* Ct8 = (_Float16*)((char*)d_ws + 65536);  // 64*256*2 = 32 KB

  s4_prep<<<65, 256, 0, stream>>>(A, B, C, log_dt, H8, Ct8);
  s4_main<<<512, 256, 0, stream>>>(x, H8, Ct8, D, log_dt, out);
}